// Round 8
// baseline (243.125 us; speedup 1.0000x reference)
//
#include <hip/hip_runtime.h>
#include <hip/hip_bf16.h>

typedef __hip_bfloat16 bf16;
typedef __attribute__((ext_vector_type(8))) short bf16x8;   // MFMA A/B frag (8 bf16)
typedef __attribute__((ext_vector_type(4))) float f32x4;    // MFMA C/D frag

#define LN_EPS 1e-5f
#define ATT_EPS 1e-8f

__device__ __forceinline__ float bflo(unsigned u){ union{unsigned i;float f;}c; c.i=u<<16; return c.f; }
__device__ __forceinline__ float bfhi(unsigned u){ union{unsigned i;float f;}c; c.i=u&0xffff0000u; return c.f; }
__device__ __forceinline__ float bf2f(bf16 h){ return __bfloat162float(h); }
__device__ __forceinline__ unsigned f2bfbits(float f){
    bf16 h = __float2bfloat16(f);
    unsigned short s; __builtin_memcpy(&s, &h, 2);
    return (unsigned)s;
}
__device__ __forceinline__ int detect_isf(const void* niw){
    unsigned u0; __builtin_memcpy(&u0, niw, 4);
    return (u0 == 0x3F800000u) ? 1 : 0;
}

__device__ __forceinline__ float getv(const void* p, long i, int isf){
    if (isf) return ((const float*)p)[i];
    return bf2f(((const bf16*)p)[i]);
}
__device__ __forceinline__ void get8(const void* p, long i, int isf, float* o){
    if (isf){
        __builtin_memcpy(o, (const float*)p + i, 32);
    } else {
        unsigned u[4];
        __builtin_memcpy(u, (const bf16*)p + i, 16);
        o[0]=bflo(u[0]); o[1]=bfhi(u[0]); o[2]=bflo(u[1]); o[3]=bfhi(u[1]);
        o[4]=bflo(u[2]); o[5]=bfhi(u[2]); o[6]=bflo(u[3]); o[7]=bfhi(u[3]);
    }
}
__device__ __forceinline__ void load4f(const float* p, float* o){ __builtin_memcpy(o, p, 16); }
__device__ __forceinline__ void store4f(float* p, const float* v){ __builtin_memcpy(p, v, 16); }

__device__ __forceinline__ void wred2(float& a, float& b){
    #pragma unroll
    for (int m = 32; m > 0; m >>= 1){
        a += __shfl_xor(a, m, 64);
        b += __shfl_xor(b, m, 64);
    }
}

// -------- phase D: kq = (shlns @ Wq) @ Wk^T * scale; wkq=w_c*kq (bf16 row),
// U=sum wkq, V=sum b_c*kq; zero P2 slice, t0, t1. Needs redQ[16*128], qsh[128], redUV[8].
__device__ __forceinline__ void phaseD2(
        int b, int s, int t, const float* shlns,
        const void* __restrict__ Wq, const void* __restrict__ Wk,
        const void* __restrict__ niw, const void* __restrict__ nib, int isf,
        bf16* __restrict__ wkqb, float* __restrict__ Ug, float* __restrict__ Vg,
        float* __restrict__ P2, float* __restrict__ t0g, float* __restrict__ t1g,
        float* redQ, float* qsh, float* redUV){
    // stage 1: q[d'] = sum_d shlns[d]*Wq[d][d']   (K-split 16 x 16, 8 outputs/thread)
    {
        int g = t & 15, ks = t >> 4;
        float a8[8] = {0,0,0,0,0,0,0,0};
        #pragma unroll
        for (int j = 0; j < 8; j++){
            int d = ks*8 + j;
            float w8[8]; get8(Wq, (long)d*128 + g*8, isf, w8);
            float pv = shlns[d];
            #pragma unroll
            for (int k = 0; k < 8; k++) a8[k] += pv*w8[k];
        }
        store4f(&redQ[ks*128 + g*8], a8);
        store4f(&redQ[ks*128 + g*8 + 4], a8+4);
    }
    __syncthreads();
    if (t < 128){
        float qv = 0.f;
        #pragma unroll
        for (int ks = 0; ks < 16; ks++) qv += redQ[ks*128 + t];
        qsh[t] = qv * 0.08838834764831845f;    // fold scale = D^-0.5
    }
    __syncthreads();
    // stage 2: kq[c] = sum_{d'} qsh[d'] * Wk[c][d']  (contiguous Wk rows)
    int c = t;
    float kqc = 0.f;
    for (int d0 = 0; d0 < 128; d0 += 8){
        float w8[8]; get8(Wk, (long)c*128 + d0, isf, w8);
        float qa[4], qb[4]; load4f(qsh + d0, qa); load4f(qsh + d0 + 4, qb);
        kqc += w8[0]*qa[0]+w8[1]*qa[1]+w8[2]*qa[2]+w8[3]*qa[3]
             + w8[4]*qb[0]+w8[5]*qb[1]+w8[6]*qb[2]+w8[7]*qb[3];
    }
    float wc = getv(niw, c, isf), bc = getv(nib, c, isf);
    float wkq = wc*kqc, vq = bc*kqc;
    float uu = wkq, vv = vq;
    wred2(uu, vv);
    int wid = t >> 6, lane = t & 63;
    if (lane == 0){ redUV[wid*2] = uu; redUV[wid*2+1] = vv; }
    wkqb[((long)b*16 + s)*256 + c] = __float2bfloat16(wkq);
    int bsI = b*10 + s;
    P2[bsI*256 + c] = 0.f;
    __syncthreads();
    if (t == 0){
        Ug[bsI] = redUV[0] + redUV[2] + redUV[4] + redUV[6];
        Vg[bsI] = redUV[1] + redUV[3] + redUV[5] + redUV[7];
        t0g[bsI] = 0.f; t1g[bsI] = 0.f;
    }
}

// -------- prep: slots init, LN(slots), phase D for iter 0; zero wkqb pad rows. grid 160
__global__ __launch_bounds__(256) void k_prep(
        const void* __restrict__ noise, const void* __restrict__ smu,
        const void* __restrict__ sls, const void* __restrict__ nsw,
        const void* __restrict__ nsb, const void* __restrict__ niw,
        const void* __restrict__ nib, const void* __restrict__ Wq,
        const void* __restrict__ Wk, float* __restrict__ slots,
        bf16* __restrict__ wkqb, float* __restrict__ Ug, float* __restrict__ Vg,
        float* __restrict__ P2, float* __restrict__ t0g, float* __restrict__ t1g){
    int isf = detect_isf(niw);
    int bs = blockIdx.x, t = threadIdx.x;
    int b = bs/10, s = bs - b*10;
    __shared__ __align__(16) float shlns[128];
    __shared__ __align__(16) float redQ[16*128];
    __shared__ __align__(16) float qsh[128];
    __shared__ float red[2][2];
    __shared__ float redUV[8];
    if (t < 128){
        float sv = getv(smu,t,isf) + __expf(getv(sls,t,isf)) * getv(noise,(long)bs*128+t,isf);
        slots[bs*128 + t] = sv;
        shlns[t] = sv;
        float su = sv, sq = sv*sv;
        wred2(su, sq);
        int wid = t >> 6, lane = t & 63;
        if (lane == 0){ red[wid][0]=su; red[wid][1]=sq; }
    }
    __syncthreads();
    if (t < 128){
        float su = red[0][0]+red[1][0], sq = red[0][1]+red[1][1];
        float m = su*(1.f/128.f), var = sq*(1.f/128.f) - m*m;
        float ri = rsqrtf(var + LN_EPS);
        shlns[t] = (shlns[t] - m)*ri*getv(nsw,t,isf) + getv(nsb,t,isf);
    }
    __syncthreads();
    phaseD2(b, s, t, shlns, Wq, Wk, niw, nib, isf, wkqb, Ug, Vg, P2, t0g, t1g,
            redQ, qsh, redUV);
    if (s == 0){
        #pragma unroll
        for (int r = 10; r < 16; r++)
            wkqb[((long)b*16 + r)*256 + t] = __float2bfloat16(0.f);
    }
}

// -------- attention: 64-px tile/block. Stage raw obs (->bf16), inline LN stats,
// MFMA logits vs wkq frags, shuffle softmax, MFMA phase-2 (attn^T @ x).
// grid (64 tiles, 16 b), 256 thr. LDS ~38.9 KB -> 4 blocks/CU
__global__ __launch_bounds__(256) void k_attn6(
        const void* __restrict__ obs, const bf16* __restrict__ wkqb,
        const float* __restrict__ Ug, const float* __restrict__ Vg,
        const void* __restrict__ niw, float* __restrict__ P2,
        float* __restrict__ t0g, float* __restrict__ t1g){
    int isf = detect_isf(niw);
    int tile = blockIdx.x, b = blockIdx.y, t = threadIdx.x;
    int w = t >> 6, l = t & 63;
    __shared__ unsigned sxn[64*132];              // raw x tile [px][132 dw] bf16 pairs
    __shared__ __align__(16) float attnP[64*16];  // attn*ri, [px][slot16] (cols>=10 zero)
    __shared__ float muri[128];                   // mu,ri per px
    __shared__ float denp0[4][16], denp1[4][16];

    // stage obs tile (convert to bf16 if fp32)
    if (isf){
        const float* gx = (const float*)obs + ((long)b*4096 + tile*64)*256;
        #pragma unroll
        for (int i = 0; i < 8; i++){
            int Ld = t*4 + i*1024;
            int px = Ld >> 7, col = Ld & 127;
            float f8[8];
            __builtin_memcpy(f8, gx + (long)px*256 + col*2, 32);
            unsigned pk[4];
            #pragma unroll
            for (int k2=0;k2<4;k2++)
                pk[k2] = (f2bfbits(f8[2*k2+1])<<16) | f2bfbits(f8[2*k2]);
            __builtin_memcpy(&sxn[px*132 + col], pk, 16);
        }
    } else {
        const unsigned* gx = (const unsigned*)obs + ((long)b*4096 + tile*64)*128;
        #pragma unroll
        for (int i = 0; i < 8; i++){
            int Ld = t*4 + i*1024;
            int px = Ld >> 7, col = Ld & 127;
            unsigned tmp[4];
            __builtin_memcpy(tmp, gx + Ld, 16);
            __builtin_memcpy(&sxn[px*132 + col], tmp, 16);
        }
    }
    // B-frags (wkq): lane (s=l&15, q) reads 8 contiguous c per K-step
    bf16x8 bfr[8];
    {
        int s = l & 15, q = (l >> 4) & 3;
        const bf16* base = wkqb + ((long)b*16 + s)*256 + q*8;
        #pragma unroll
        for (int ks = 0; ks < 8; ks++)
            __builtin_memcpy(&bfr[ks], base + ks*32, 16);
    }
    __syncthreads();

    // inline LN stats per px (from staged bf16 tile)
    {
        int px = t >> 2, q = t & 3;
        float su = 0.f, sq = 0.f;
        #pragma unroll
        for (int j = 0; j < 8; j++){
            unsigned d4[4];
            __builtin_memcpy(d4, &sxn[px*132 + q*32 + j*4], 16);
            #pragma unroll
            for (int k2=0;k2<4;k2++){
                float a0 = bflo(d4[k2]), a1 = bfhi(d4[k2]);
                su += a0 + a1; sq += a0*a0 + a1*a1;
            }
        }
        su += __shfl_xor(su,1,64); sq += __shfl_xor(sq,1,64);
        su += __shfl_xor(su,2,64); sq += __shfl_xor(sq,2,64);
        if (q == 0){
            float m = su*(1.f/256.f);
            float ri = rsqrtf(sq*(1.f/256.f) - m*m + LN_EPS);
            muri[px*2] = m; muri[px*2+1] = ri;
        }
    }
    __syncthreads();

    // GEMM1: R[16px][16s] raw-x @ wkq (8 MFMAs per wave)
    f32x4 acc = {0.f,0.f,0.f,0.f};
    {
        int m = l & 15, q = (l >> 4) & 3;
        int rowbase = (w*16 + m)*132;
        #pragma unroll
        for (int ks = 0; ks < 8; ks++){
            bf16x8 af;
            __builtin_memcpy(&af, &sxn[rowbase + ks*16 + q*4], 16);
            acc = __builtin_amdgcn_mfma_f32_16x16x32_bf16(af, bfr[ks], acc, 0, 0, 0);
        }
    }

    // softmax over slots with LN affine correction; t0,t1 partials
    {
        int col = l & 15, q = (l >> 4) & 3;
        float Uv = 0.f, Vv = 0.f;
        if (col < 10){ Uv = Ug[b*10 + col]; Vv = Vg[b*10 + col]; }
        float pden0 = 0.f, pden1 = 0.f;
        #pragma unroll
        for (int reg = 0; reg < 4; reg++){
            int px = w*16 + q*4 + reg;
            float mr[2]; __builtin_memcpy(mr, &muri[px*2], 8);
            float lg = (col < 10) ? (mr[1]*acc[reg] - mr[1]*mr[0]*Uv + Vv) : -1e30f;
            float mx = lg;
            mx = fmaxf(mx, __shfl_xor(mx,1,64));
            mx = fmaxf(mx, __shfl_xor(mx,2,64));
            mx = fmaxf(mx, __shfl_xor(mx,4,64));
            mx = fmaxf(mx, __shfl_xor(mx,8,64));
            float e = (col < 10) ? __expf(lg - mx) : 0.f;
            float sm = e;
            sm += __shfl_xor(sm,1,64);
            sm += __shfl_xor(sm,2,64);
            sm += __shfl_xor(sm,4,64);
            sm += __shfl_xor(sm,8,64);
            float a = e / sm;
            attnP[px*16 + col] = a*mr[1];          // zero for col>=10 (a==0)
            pden0 += a;
            pden1 += a*mr[1]*mr[0];
        }
        pden0 += __shfl_xor(pden0,16,64); pden0 += __shfl_xor(pden0,32,64);
        pden1 += __shfl_xor(pden1,16,64); pden1 += __shfl_xor(pden1,32,64);
        if (l < 10){ denp0[w][l] = pden0; denp1[w][l] = pden1; }
    }
    __syncthreads();
    if (t < 10){
        atomicAdd(&t0g[b*10 + t], denp0[0][t]+denp0[1][t]+denp0[2][t]+denp0[3][t]);
        atomicAdd(&t1g[b*10 + t], denp1[0][t]+denp1[1][t]+denp1[2][t]+denp1[3][t]);
    }

    // phase 2 (MFMA): P2[s][c] += sum_px attnP[s][px] * x[px][c]
    // D[m=s][n=c]: A[m=s][k=px] from attnP; B[k=px][col=c] from natural sxn (u16)
    {
        int col = l & 15, q = (l >> 4) & 3;
        bf16x8 afr[2];
        #pragma unroll
        for (int ks = 0; ks < 2; ks++){
            short tmpa[8];
            #pragma unroll
            for (int j = 0; j < 8; j++){
                int px = ks*32 + q*8 + j;
                tmpa[j] = (short)f2bfbits(attnP[px*16 + col]);
            }
            __builtin_memcpy(&afr[ks], tmpa, 16);
        }
        const unsigned short* xs = (const unsigned short*)sxn;
        #pragma unroll
        for (int nt = 0; nt < 4; nt++){
            int cfull = w*64 + nt*16 + col;
            f32x4 c2 = {0.f,0.f,0.f,0.f};
            #pragma unroll
            for (int ks = 0; ks < 2; ks++){
                short tmpb[8];
                #pragma unroll
                for (int j = 0; j < 8; j++){
                    int px = ks*32 + q*8 + j;
                    tmpb[j] = (short)xs[px*264 + cfull];
                }
                bf16x8 bf_;
                __builtin_memcpy(&bf_, tmpb, 16);
                c2 = __builtin_amdgcn_mfma_f32_16x16x32_bf16(afr[ks], bf_, c2, 0, 0, 0);
            }
            #pragma unroll
            for (int reg = 0; reg < 4; reg++){
                int s = q*4 + reg;
                if (s < 10)
                    atomicAdd(&P2[b*2560 + s*256 + cfull], c2[reg]);
            }
        }
    }
}

// -------- slot update (+ fused heads on last iter, + phase D otherwise). grid 160
__global__ __launch_bounds__(256) void k_slot(
        float* __restrict__ slots, float* __restrict__ P2,
        float* __restrict__ t0g, float* __restrict__ t1g,
        const void* __restrict__ Wv,
        const void* __restrict__ nmw, const void* __restrict__ nmb,
        const void* __restrict__ w1, const void* __restrict__ b1,
        const void* __restrict__ w2, const void* __restrict__ b2,
        const void* __restrict__ nsw, const void* __restrict__ nsb,
        const void* __restrict__ niw, const void* __restrict__ nib,
        const void* __restrict__ Wq, const void* __restrict__ Wk,
        const void* __restrict__ pw1, const void* __restrict__ pb1,
        const void* __restrict__ pw2, const void* __restrict__ pb2,
        const void* __restrict__ tw, const void* __restrict__ tb,
        bf16* __restrict__ wkqb, float* __restrict__ Ug, float* __restrict__ Vg,
        void* __restrict__ out, int last){
    int isf = detect_isf(niw);
    int bs = blockIdx.x, t = threadIdx.x;
    int b = bs/10, s = bs - b*10;
    __shared__ __align__(16) float pr[256];
    __shared__ __align__(16) float redA[16*128];   // also redQ in phaseD
    __shared__ __align__(16) float redB[8*256];
    __shared__ __align__(16) float redT[8*32];
    __shared__ __align__(16) float hld[128];
    __shared__ __align__(16) float hid[256];
    __shared__ __align__(16) float shlns[128];
    __shared__ __align__(16) float qsh[128];
    __shared__ float red[4][2];
    __shared__ float redUV[8];

    float t0v = t0g[bs], t1v = t1g[bs];
    float wc = getv(niw,t,isf), bcv = getv(nib,t,isf);
    pr[t] = (P2[bs*256 + t] - t1v)*wc + t0v*bcv;   // praw with LN fold-back
    __syncthreads();

    // phase A: upd = pr @ Wv  (K-split 16x16, 8 outputs/thread)
    {
        int g = t & 15, ks = t >> 4;
        int d0 = g*8;
        float a8[8] = {0,0,0,0,0,0,0,0};
        #pragma unroll
        for (int j=0;j<16;j++){
            int c2 = ks*16 + j;
            float w8[8]; get8(Wv, (long)c2*128 + d0, isf, w8);
            float pv = pr[c2];
            #pragma unroll
            for (int k=0;k<8;k++) a8[k] += pv*w8[k];
        }
        store4f(&redA[ks*128 + d0], a8);
        store4f(&redA[ks*128 + d0 + 4], a8+4);
    }
    __syncthreads();
    float dv = t0v + ATT_EPS;
    float sn = 0.f;
    if (t < 128){
        float u = 0.f;
        #pragma unroll
        for (int ks=0;ks<16;ks++) u += redA[ks*128 + t];
        sn = slots[bs*128 + t] + u/dv;
    }
    float v = (t < 128) ? sn : 0.f;
    float su = v, sq = v*v;
    wred2(su, sq);
    int wid = t >> 6, lane = t & 63;
    if (lane == 0){ red[wid][0]=su; red[wid][1]=sq; }
    __syncthreads();
    su = red[0][0]+red[1][0]+red[2][0]+red[3][0];
    sq = red[0][1]+red[1][1]+red[2][1]+red[3][1];
    float mu = su*(1.f/128.f), var = sq*(1.f/128.f) - mu*mu;
    float rinv = rsqrtf(var + LN_EPS);
    if (t < 128) hld[t] = (v-mu)*rinv*getv(nmw,t,isf) + getv(nmb,t,isf);
    __syncthreads();

    // phase B: hid = relu(b1 + hld @ w1)
    {
        int g = t & 31, ks = t >> 5;
        int h0 = g*8;
        float a8[8] = {0,0,0,0,0,0,0,0};
        #pragma unroll
        for (int j=0;j<16;j++){
            int d = ks*16 + j;
            float w8[8]; get8(w1, (long)d*256 + h0, isf, w8);
            float hv = hld[d];
            #pragma unroll
            for (int k=0;k<8;k++) a8[k] += hv*w8[k];
        }
        store4f(&redB[ks*256 + h0], a8);
        store4f(&redB[ks*256 + h0 + 4], a8+4);
    }
    __syncthreads();
    {
        float hb = getv(b1,t,isf);
        #pragma unroll
        for (int ks=0;ks<8;ks++) hb += redB[ks*256 + t];
        hid[t] = fmaxf(hb, 0.f);
    }
    __syncthreads();

    // phase C: out = b2 + hid @ w2
    {
        int g = t & 15, ks = t >> 4;
        int d0 = g*8;
        float a8[8] = {0,0,0,0,0,0,0,0};
        #pragma unroll
        for (int j=0;j<16;j++){
            int h = ks*16 + j;
            float w8[8]; get8(w2, (long)h*128 + d0, isf, w8);
            float hv = hid[h];
            #pragma unroll
            for (int k=0;k<8;k++) a8[k] += hv*w8[k];
        }
        store4f(&redA[ks*128 + d0], a8);
        store4f(&redA[ks*128 + d0 + 4], a8+4);
    }
    __syncthreads();
    float v2 = 0.f;
    if (t < 128){
        float o = getv(b2,t,isf);
        #pragma unroll
        for (int ks=0;ks<16;ks++) o += redA[ks*128 + t];
        v2 = sn + o;
    }

    if (!last){
        if (t < 128) slots[bs*128 + t] = v2;
        // LN(new slots) -> shlns, then phase D (kq for next iteration)
        float s2 = v2, ss2 = v2*v2;
        wred2(s2, ss2);
        if (lane == 0){ red[wid][0]=s2; red[wid][1]=ss2; }
        __syncthreads();
        s2 = red[0][0]+red[1][0]+red[2][0]+red[3][0];
        ss2 = red[0][1]+red[1][1]+red[2][1]+red[3][1];
        float mu2 = s2*(1.f/128.f), var2 = ss2*(1.f/128.f) - mu2*mu2;
        float ri2 = rsqrtf(var2 + LN_EPS);
        if (t < 128)
            shlns[t] = (v2 - mu2)*ri2*getv(nsw,t,isf) + getv(nsb,t,isf);
        __syncthreads();
        phaseD2(b, s, t, shlns, Wq, Wk, niw, nib, isf, wkqb, Ug, Vg, P2, t0g, t1g,
                redA, qsh, redUV);
    } else {
        // fused heads
        if (t < 128) shlns[t] = v2;
        __syncthreads();
        {
            int g = t & 31, ks = t >> 5;
            int h0 = g*8;
            float a8[8] = {0,0,0,0,0,0,0,0};
            #pragma unroll
            for (int j=0;j<16;j++){
                int d = ks*16 + j;
                float w8[8]; get8(pw1, (long)d*256 + h0, isf, w8);
                float hv = shlns[d];
                #pragma unroll
                for (int k=0;k<8;k++) a8[k] += hv*w8[k];
            }
            store4f(&redB[ks*256 + h0], a8);
            store4f(&redB[ks*256 + h0 + 4], a8+4);
        }
        __syncthreads();
        {
            float hb = getv(pb1,t,isf);
            #pragma unroll
            for (int ks=0;ks<8;ks++) hb += redB[ks*256 + t];
            hid[t] = fmaxf(hb, 0.f);
        }
        __syncthreads();
        {
            int g = t & 15, ks = t >> 4;
            int d0 = g*8;
            float a8[8] = {0,0,0,0,0,0,0,0};
            #pragma unroll
            for (int j=0;j<16;j++){
                int h = ks*16 + j;
                float w8[8]; get8(pw2, (long)h*128 + d0, isf, w8);
                float hv = hid[h];
                #pragma unroll
                for (int k=0;k<8;k++) a8[k] += hv*w8[k];
            }
            store4f(&redA[ks*128 + d0], a8);
            store4f(&redA[ks*128 + d0 + 4], a8+4);
        }
        {
            int ot = t & 31, ks = t >> 5;
            float a = 0.f;
            if (ot < 20){
                #pragma unroll
                for (int j=0;j<16;j++){
                    int d = ks*16 + j;
                    a += shlns[d]*getv(tw, (long)d*20 + ot, isf);
                }
            }
            redT[ks*32 + ot] = a;
        }
        __syncthreads();
        if (t < 128){
            float o = getv(pb2,t,isf);
            #pragma unroll
            for (int ks=0;ks<16;ks++) o += redA[ks*128 + t];
            int idx = bs*128 + t;
            if (isf) ((float*)out)[idx] = o; else ((bf16*)out)[idx] = __float2bfloat16(o);
        }
        if (t < 20){
            float o = getv(tb,t,isf);
            #pragma unroll
            for (int ks=0;ks<8;ks++) o += redT[ks*32 + t];
            int idx = 16*10*128 + bs*20 + t;
            if (isf) ((float*)out)[idx] = o; else ((bf16*)out)[idx] = __float2bfloat16(o);
        }
    }
}

extern "C" void kernel_launch(void* const* d_in, const int* in_sizes, int n_in,
                              void* d_out, int out_size, void* d_ws, size_t ws_size,
                              hipStream_t stream) {
    const void* obs   = d_in[0];
    const void* noise = d_in[1];
    const void* smu   = d_in[2];
    const void* sls   = d_in[3];
    const void* niw   = d_in[4];
    const void* nib   = d_in[5];
    const void* nsw   = d_in[6];
    const void* nsb   = d_in[7];
    const void* nmw   = d_in[8];
    const void* nmb   = d_in[9];
    const void* Wq    = d_in[10];
    const void* Wk    = d_in[11];
    const void* Wv    = d_in[12];
    const void* w1    = d_in[13];
    const void* b1    = d_in[14];
    const void* w2    = d_in[15];
    const void* b2    = d_in[16];
    const void* pw1   = d_in[17];
    const void* pb1   = d_in[18];
    const void* pw2   = d_in[19];
    const void* pb2   = d_in[20];
    const void* tw    = d_in[21];
    const void* tb    = d_in[22];

    char* ws = (char*)d_ws;
    float* t0g   = (float*)(ws);                // @0       (1024 B, 160 used)
    float* t1g   = (float*)(ws + 1024);         // @1024    (1024 B)
    float* Ug    = (float*)(ws + 2048);         // @2048    (1024 B)
    float* Vg    = (float*)(ws + 3072);         // @3072    (1024 B)
    float* slots = (float*)(ws + 4096);         // @4096    (81920 B)
    float* P2    = (float*)(ws + 86016);        // @86016   (163840 B)
    bf16*  wkqb  = (bf16*) (ws + 249856);       // @249856  (131072 B) -> ~372 KB total

    k_prep<<<160, 256, 0, stream>>>(noise, smu, sls, nsw, nsb, niw, nib, Wq, Wk,
                                    slots, wkqb, Ug, Vg, P2, t0g, t1g);
    for (int it = 0; it < 3; it++){
        k_attn6<<<dim3(64, 16), 256, 0, stream>>>(obs, wkqb, Ug, Vg, niw, P2, t0g, t1g);
        k_slot<<<160, 256, 0, stream>>>(slots, P2, t0g, t1g, Wv, nmw, nmb,
                                        w1, b1, w2, b2, nsw, nsb, niw, nib,
                                        Wq, Wk, pw1, pb1, pw2, pb2, tw, tb,
                                        wkqb, Ug, Vg, d_out, (it == 2) ? 1 : 0);
    }
}